// Round 6
// baseline (883.691 us; speedup 1.0000x reference)
//
#include <hip/hip_runtime.h>
#include <cmath>

// Problem constants
#define BATCH 4
#define SEQ   2048
#define EMB   2048
#define NH    16
#define HD    128
#define MDIM  (BATCH*SEQ)   // 8192
#define KDIM  EMB           // 2048
#define NDIM  EMB           // 2048

typedef __bf16 bf16x8 __attribute__((ext_vector_type(8)));
typedef float  f32x4  __attribute__((ext_vector_type(4)));

__device__ __forceinline__ ushort bf16rne(float f) {
  unsigned u = __builtin_bit_cast(unsigned, f);
  u += 0x7fffu + ((u >> 16) & 1u);
  return (ushort)(u >> 16);
}

// global -> LDS direct DMA, 16 bytes per lane.
// LDS dest must be wave-uniform base; HW adds lane*16.
__device__ __forceinline__ void gld_lds16(const ushort* g, ushort* l) {
  __builtin_amdgcn_global_load_lds(
      (const __attribute__((address_space(1))) unsigned int*)g,
      (__attribute__((address_space(3))) unsigned int*)l, 16, 0, 0);
}

// ---------------- fp32 -> bf16 convert (vector x4) ----------------
__global__ __launch_bounds__(256) void cvt_bf16(const float* __restrict__ in,
                                                ushort* __restrict__ out) {
  int i = (blockIdx.x * 256 + threadIdx.x) * 4;
  float4 v = *(const float4*)(in + i);
  ushort4 o;
  o.x = bf16rne(v.x); o.y = bf16rne(v.y); o.z = bf16rne(v.z); o.w = bf16rne(v.w);
  *(ushort4*)(out + i) = o;
}

// ---------------- NT GEMM: C[M,N] = A[M,K] * B[N,K]^T + bias ----------------
// R6: 256x256 tile, BK=32, 4-deep LDS K-tile ring (128 KB), 8 waves,
// counted-vmcnt pipeline (T3+T4): 3-tile lookahead, ONE raw s_barrier per
// K-tile, vmcnt(8) steady state (4 loads/thread/tile, 2 tiles in flight).
// Stage issued AFTER the barrier => buffer overwrite is safe (all waves
// finished reading it last iteration). Tail drains vmcnt 4 -> 0.
// Grid = (32,8) = 256 blocks = exactly 1/CU.
// MODE 0: fp32 plain row-major [M,N]
// MODE 1: bf16 to [B,H,S,D]   (m = b*S+s, n = h*D+d)
// MODE 2: bf16 to [B,H,D,S]   (transposed store via LDS scratch aliased on As)
template<int MODE>
__global__ __launch_bounds__(512, 2)
void gemm_nt(const ushort* __restrict__ A, const ushort* __restrict__ Bm,
             const float* __restrict__ bias, void* __restrict__ out) {
  __shared__ ushort As[4 * 256 * 32];   // 64 KB: ring of 4 A K-tiles [256][32]
  __shared__ ushort Bs[4 * 256 * 32];   // 64 KB: ring of 4 B K-tiles

  const int tid  = threadIdx.x;
  const int wave = tid >> 6, lane = tid & 63;
  const int l15  = lane & 15, quad = lane >> 4;
  const int m0 = blockIdx.x * 256, n0 = blockIdx.y * 256;
  const int wr2 = (wave >> 2) * 128;   // wave row block (2 x 128)
  const int wc2 = (wave & 3) * 64;     // wave col block (4 x 64)

  const f32x4 zero4 = {0.f, 0.f, 0.f, 0.f};
  f32x4 acc[8][4];
#pragma unroll
  for (int i = 0; i < 8; ++i)
#pragma unroll
    for (int j = 0; j < 4; ++j) acc[i][j] = zero4;

  // staging: per K-tile = A 16KB + B 16KB = 4 block-wide 8KB DMA ops
  // (4 gld_lds16 per thread per tile). dest ushort ofs = c*8192 + p*4096 + tid*8
  // -> row = p*128 + tid/4, col = (tid&3)*8  (matches src).
  const int srow = tid >> 2, sc8 = (tid & 3) * 8;
  const int Lw   = tid & ~63;

  auto STAGE = [&](int c, int t) {
    const int kk = t * 32;
#pragma unroll
    for (int p = 0; p < 2; ++p) {
      gld_lds16(A  + (size_t)(m0 + p*128 + srow) * KDIM + kk + sc8,
                As + c*8192 + (p*512 + Lw) * 8);
      gld_lds16(Bm + (size_t)(n0 + p*128 + srow) * KDIM + kk + sc8,
                Bs + c*8192 + (p*512 + Lw) * 8);
    }
  };

  const int NT = KDIM / 32;   // 64 K-tiles
  STAGE(0, 0); STAGE(1, 1); STAGE(2, 2);   // prologue: 3-deep

  for (int t = 0; t < NT; ++t) {
    // drain so that tile t's 4 loads (per wave) are complete; newer tiles
    // (t+1, t+2: 8 loads) may stay in flight across barriers (T4).
    if (t + 2 < NT)      asm volatile("s_waitcnt vmcnt(8)" ::: "memory");
    else if (t + 1 < NT) asm volatile("s_waitcnt vmcnt(4)" ::: "memory");
    else                 asm volatile("s_waitcnt vmcnt(0)" ::: "memory");
    asm volatile("s_barrier" ::: "memory");   // publish; memory clobber pins order

    if (t + 3 < NT) STAGE((t + 3) & 3, t + 3);   // overwrites buf read at t-1: safe

    const ushort* Ab = As + (t & 3) * 8192;
    const ushort* Bb = Bs + (t & 3) * 8192;
    bf16x8 af[8], bf[4];
#pragma unroll
    for (int i = 0; i < 8; ++i)
      af[i] = __builtin_bit_cast(bf16x8,
                *(const int4*)(Ab + (wr2 + i*16 + l15) * 32 + quad*8));
#pragma unroll
    for (int j = 0; j < 4; ++j)
      bf[j] = __builtin_bit_cast(bf16x8,
                *(const int4*)(Bb + (wc2 + j*16 + l15) * 32 + quad*8));
    __builtin_amdgcn_s_setprio(1);
#pragma unroll
    for (int i = 0; i < 8; ++i)
#pragma unroll
      for (int j = 0; j < 4; ++j)
        acc[i][j] = __builtin_amdgcn_mfma_f32_16x16x32_bf16(af[i], bf[j], acc[i][j], 0, 0, 0);
    __builtin_amdgcn_s_setprio(0);
  }

  // Epilogue. C/D layout: col = lane&15, row = quad*4 + r  (m89/m91 verified)
  if constexpr (MODE == 0) {
    float* O = (float*)out;
#pragma unroll
    for (int i = 0; i < 8; ++i)
#pragma unroll
      for (int j = 0; j < 4; ++j) {
        int n = n0 + wc2 + j*16 + l15;
        float bb = bias[n];
#pragma unroll
        for (int r = 0; r < 4; ++r) {
          int m = m0 + wr2 + i*16 + quad*4 + r;
          O[(size_t)m * NDIM + n] = acc[i][j][r] + bb;
        }
      }
  } else if constexpr (MODE == 1) {
    ushort* O = (ushort*)out;
#pragma unroll
    for (int i = 0; i < 8; ++i)
#pragma unroll
      for (int j = 0; j < 4; ++j) {
        int n = n0 + wc2 + j*16 + l15;
        float bb = bias[n];
        int h = n >> 7, d = n & 127;
#pragma unroll
        for (int r = 0; r < 4; ++r) {
          int m = m0 + wr2 + i*16 + quad*4 + r;
          int b = m >> 11, sr = m & 2047;
          O[(((size_t)(b*NH + h) * SEQ + sr) << 7) + d] = bf16rne(acc[i][j][r] + bb);
        }
      }
  } else {  // MODE 2: [B,H,D,S] via per-wave LDS 16x16 transpose
    // scratch aliased on As buffer 0 (last read at t=60; every wave passed
    // later barriers before any wave reaches here; no stage targets buf0
    // after tile 60). 8 waves x 16 x 17 floats = 8704 B, wave-private.
    float* TtF = (float*)As;
    ushort* O = (ushort*)out;
#pragma unroll
    for (int i = 0; i < 8; ++i)
#pragma unroll
      for (int j = 0; j < 4; ++j) {
        int n = n0 + wc2 + j*16 + l15;
        float bb = bias[n];
#pragma unroll
        for (int r = 0; r < 4; ++r)
          TtF[(wave*16 + l15)*17 + quad*4 + r] = acc[i][j][r] + bb;  // [d_loc][s_loc]
#pragma unroll
        for (int r = 0; r < 4; ++r) {
          int dl = quad*4 + r, sl = l15;
          float v = TtF[(wave*16 + dl)*17 + sl];
          int m = m0 + wr2 + i*16 + sl;
          int b = m >> 11, sr = m & 2047;
          int n2 = n0 + wc2 + j*16 + dl;
          int h = n2 >> 7, d = n2 & 127;
          O[((size_t)(b*NH + h) * HD + d) * SEQ + sr] = bf16rne(v);
        }
      }
  }
}

// ---------------- fused attention (no-max online softmax) ----------------
// (unchanged from R5 best: QBLK=128, 8 waves, XOR swizzle, setprio, 214 us)
__global__ __launch_bounds__(512, 2)
void attn_kernel(const ushort* __restrict__ Qh, const ushort* __restrict__ Kh,
                 const ushort* __restrict__ Vt, const float* __restrict__ noise,
                 ushort* __restrict__ ctxn, float scale, float ns) {
  __shared__ ushort Ks[64 * 128];    // [k_row][d], row 256B, swizzled
  __shared__ ushort Vs[128 * 64];    // [d][k_col], row 128B, swizzled
  __shared__ ushort Ps[128 * 64];    // [q][k],     row 128B, swizzled

  const int tid  = threadIdx.x;
  const int wave = tid >> 6, lane = tid & 63;
  const int l15  = lane & 15, quad = lane >> 4;
  const int q0 = blockIdx.x * 128;
  const int bh = blockIdx.y;                  // b*NH + h
  const int b  = bh >> 4, h = bh & 15;

  bf16x8 qf[4];
  {
    const int qrow = q0 + wave*16 + l15;
    const ushort* qp = Qh + ((size_t)bh * SEQ + qrow) * HD;
#pragma unroll
    for (int ks = 0; ks < 4; ++ks)
      qf[ks] = __builtin_bit_cast(bf16x8, *(const int4*)(qp + ks*32 + quad*8));
  }

  const f32x4 zero4 = {0.f, 0.f, 0.f, 0.f};
  f32x4 o[8];
#pragma unroll
  for (int nb = 0; nb < 8; ++nb) o[nb] = zero4;
  float rs[4] = {0.f, 0.f, 0.f, 0.f};

  for (int k0 = 0; k0 < SEQ; k0 += 64) {
#pragma unroll
    for (int it = 0; it < 2; ++it) {
      int L = it * 512 + tid;
      int r = L >> 4, c8 = (L & 15) * 8;
      int4 v = *(const int4*)(Kh + ((size_t)bh * SEQ + k0 + r) * HD + c8);
      *(int4*)(&Ks[r * 128 + (c8 ^ ((r & 7) << 3))]) = v;
    }
#pragma unroll
    for (int it = 0; it < 2; ++it) {
      int L = it * 512 + tid;
      int r = L >> 3, c8 = (L & 7) * 8;
      int4 v = *(const int4*)(Vt + ((size_t)bh * HD + r) * SEQ + k0 + c8);
      *(int4*)(&Vs[r * 64 + (c8 ^ ((r & 7) << 3))]) = v;
    }
    __syncthreads();

#pragma unroll
    for (int ct = 0; ct < 4; ++ct) {
      f32x4 s = zero4;
      const int kr = ct*16 + l15;
      __builtin_amdgcn_s_setprio(1);
#pragma unroll
      for (int ks = 0; ks < 4; ++ks) {
        bf16x8 kf = __builtin_bit_cast(bf16x8,
            *(const int4*)(&Ks[kr * 128 + ((ks*32 + quad*8) ^ ((kr & 7) << 3))]));
        s = __builtin_amdgcn_mfma_f32_16x16x32_bf16(qf[ks], kf, s, 0, 0, 0);
      }
      __builtin_amdgcn_s_setprio(0);
#pragma unroll
      for (int r = 0; r < 4; ++r) {
        float p = __expf(s[r] * scale);
        rs[r] += p;
        int pr = wave*16 + quad*4 + r;
        int pc = ct*16 + l15;
        Ps[pr * 64 + (pc ^ ((pr & 7) << 3))] = bf16rne(p);
      }
    }

    __builtin_amdgcn_s_setprio(1);
#pragma unroll
    for (int ks2 = 0; ks2 < 2; ++ks2) {
      const int par = wave*16 + l15;
      bf16x8 pa = __builtin_bit_cast(bf16x8,
          *(const int4*)(&Ps[par * 64 + ((ks2*32 + quad*8) ^ ((par & 7) << 3))]));
#pragma unroll
      for (int nb = 0; nb < 8; ++nb) {
        const int vr = nb*16 + l15;
        bf16x8 vb = __builtin_bit_cast(bf16x8,
            *(const int4*)(&Vs[vr * 64 + ((ks2*32 + quad*8) ^ ((vr & 7) << 3))]));
        o[nb] = __builtin_amdgcn_mfma_f32_16x16x32_bf16(pa, vb, o[nb], 0, 0, 0);
      }
    }
    __builtin_amdgcn_s_setprio(0);
    __syncthreads();
  }

#pragma unroll
  for (int r = 0; r < 4; ++r) {
    float v = rs[r];
    v += __shfl_xor(v, 1);
    v += __shfl_xor(v, 2);
    v += __shfl_xor(v, 4);
    v += __shfl_xor(v, 8);
    rs[r] = v;
  }

#pragma unroll
  for (int r = 0; r < 4; ++r) {
    float inv = 1.0f / rs[r];
    int sg = q0 + wave*16 + quad*4 + r;
    size_t rowbase = ((size_t)(b * SEQ + sg)) * EMB + h * HD;
#pragma unroll
    for (int nb = 0; nb < 8; ++nb) {
      int e = nb*16 + l15;
      float val = o[nb][r] * inv + noise[rowbase + e] * ns;
      ctxn[rowbase + e] = bf16rne(val);
    }
  }
}

extern "C" void kernel_launch(void* const* d_in, const int* in_sizes, int n_in,
                              void* d_out, int out_size, void* d_ws, size_t ws_size,
                              hipStream_t stream) {
  const float* query = (const float*)d_in[0];
  const float* key_t = (const float*)d_in[1];
  const float* value = (const float*)d_in[2];
  const float* Wq = (const float*)d_in[3];
  const float* bq = (const float*)d_in[4];
  const float* Wk = (const float*)d_in[5];
  const float* bk = (const float*)d_in[6];
  const float* Wv = (const float*)d_in[7];
  const float* bv = (const float*)d_in[8];
  const float* Wo = (const float*)d_in[9];
  const float* bo = (const float*)d_in[10];
  const float* noise = (const float*)d_in[11];

  const size_t SZ_ACT = (size_t)MDIM * KDIM * 2;  // 33,554,432 B
  const size_t SZ_W   = (size_t)NDIM * KDIM * 2;  //  8,388,608 B
  const size_t need_full = 7 * SZ_ACT + 4 * SZ_W; // 256 MB

  char* p = (char*)d_ws;
  ushort *qb, *kb;
  if (ws_size >= need_full) {
    qb = (ushort*)p; p += SZ_ACT;
    kb = (ushort*)p; p += SZ_ACT;
  } else {
    // overlay q/k bf16 inputs on d_out (exactly 64 MB); consumed before final GEMM
    qb = (ushort*)d_out;
    kb = (ushort*)((char*)d_out + SZ_ACT);
  }
  ushort* vb   = (ushort*)p; p += SZ_ACT;
  ushort* wqb  = (ushort*)p; p += SZ_W;
  ushort* wkb  = (ushort*)p; p += SZ_W;
  ushort* wvb  = (ushort*)p; p += SZ_W;
  ushort* wob  = (ushort*)p; p += SZ_W;
  ushort* Qh   = (ushort*)p; p += SZ_ACT;
  ushort* Kh   = (ushort*)p; p += SZ_ACT;
  ushort* Vt   = (ushort*)p; p += SZ_ACT;
  ushort* ctxn = (ushort*)p; p += SZ_ACT;

  const int nAct = MDIM * KDIM;          // 16,777,216
  const int nW   = NDIM * KDIM;          //  4,194,304
  const float NS = (float)sqrt(2.0 * log(1.25 / 1e-5));
  const float SCALE = (float)(1.0 / sqrt((double)HD));

  cvt_bf16<<<dim3(nAct / 1024), dim3(256), 0, stream>>>(query, qb);
  cvt_bf16<<<dim3(nAct / 1024), dim3(256), 0, stream>>>(key_t, kb);
  cvt_bf16<<<dim3(nAct / 1024), dim3(256), 0, stream>>>(value, vb);
  cvt_bf16<<<dim3(nW / 1024),   dim3(256), 0, stream>>>(Wq, wqb);
  cvt_bf16<<<dim3(nW / 1024),   dim3(256), 0, stream>>>(Wk, wkb);
  cvt_bf16<<<dim3(nW / 1024),   dim3(256), 0, stream>>>(Wv, wvb);
  cvt_bf16<<<dim3(nW / 1024),   dim3(256), 0, stream>>>(Wo, wob);

  dim3 ggrid(MDIM / 256, NDIM / 256);   // 32 x 8 = 256 blocks = 1/CU
  gemm_nt<1><<<ggrid, dim3(512), 0, stream>>>(qb, wqb, bq, (void*)Qh);
  gemm_nt<1><<<ggrid, dim3(512), 0, stream>>>(kb, wkb, bk, (void*)Kh);
  gemm_nt<2><<<ggrid, dim3(512), 0, stream>>>(vb, wvb, bv, (void*)Vt);

  attn_kernel<<<dim3(SEQ / 128, BATCH * NH), dim3(512), 0, stream>>>(
      Qh, Kh, Vt, noise, ctxn, SCALE, NS);

  gemm_nt<0><<<ggrid, dim3(512), 0, stream>>>(ctxn, wob, bo, d_out);
}